// Round 1
// baseline (5843.166 us; speedup 1.0000x reference)
//
#include <hip/hip_runtime.h>

#define USH unsigned short
typedef __attribute__((ext_vector_type(8))) short short8;
typedef __attribute__((ext_vector_type(4))) float f32x4;

__device__ __forceinline__ USH rne_bf16(float f){
  unsigned int u = __float_as_uint(f);
  u = (u + 0x7fffu + ((u >> 16) & 1u)) >> 16;
  return (USH)u;
}
__device__ __forceinline__ float sigm(float x){ return 1.f / (1.f + __expf(-x)); }
__device__ __forceinline__ float tanh_(float x){ return 1.f - 2.f / (__expf(2.f * x) + 1.f); }

__device__ __forceinline__ void gload16(const void* g, void* l){
  __builtin_amdgcn_global_load_lds((const __attribute__((address_space(1))) unsigned int*)g,
                                   (__attribute__((address_space(3))) unsigned int*)l, 16, 0, 0);
}

// ---- prep: Wc = W_ih1 @ W_lin  (fp32 -> bf16, K-padded 34->64), bc = W_ih1@b_lin + b_ih1 + b_hh1
__global__ void k_fold(const float* __restrict__ Wih1, const float* __restrict__ Wlin,
                       const float* __restrict__ blin, const float* __restrict__ bih1,
                       const float* __restrict__ bhh1, USH* __restrict__ Wcb, float* __restrict__ bc){
  const int n = blockIdx.x;          // 0..4095
  const int t = threadIdx.x;         // 64 threads = 1 wave
  float a[34];
#pragma unroll
  for (int f = 0; f < 34; ++f) a[f] = 0.f;
  float ab = 0.f;
  for (int e = t; e < 1024; e += 64){
    const float wv = Wih1[n * 1024 + e];
    ab += wv * blin[e];
    const float* wl = Wlin + e * 34;
#pragma unroll
    for (int f = 0; f < 34; ++f) a[f] += wv * wl[f];
  }
#pragma unroll
  for (int off = 32; off > 0; off >>= 1){
    ab += __shfl_down(ab, off);
#pragma unroll
    for (int f = 0; f < 34; ++f) a[f] += __shfl_down(a[f], off);
  }
  if (t == 0){
    for (int f = 0; f < 34; ++f) Wcb[n * 64 + f] = rne_bf16(a[f]);
    for (int f = 34; f < 64; ++f) Wcb[n * 64 + f] = 0;
    bc[n] = ab + bih1[n] + bhh1[n];
  }
}

// ---- prep: weights -> bf16, b2 = b_ih2 + b_hh2
__global__ void k_convert(const float* __restrict__ Whh1, const float* __restrict__ Wih2,
                          const float* __restrict__ Whh2, const float* __restrict__ bih2,
                          const float* __restrict__ bhh2,
                          USH* __restrict__ oWhh1, USH* __restrict__ oW2a, USH* __restrict__ oW2b,
                          float* __restrict__ ob2){
  const int n = 4096 * 1024;
  for (int i = blockIdx.x * blockDim.x + threadIdx.x; i < n; i += gridDim.x * blockDim.x){
    oWhh1[i] = rne_bf16(Whh1[i]);
    oW2a[i]  = rne_bf16(Wih2[i]);
    oW2b[i]  = rne_bf16(Whh2[i]);
    if (i < 4096) ob2[i] = bih2[i] + bhh2[i];
  }
}

// ---- prep: x [B][T][34] fp32 -> xb [T][B][64] bf16 (zero-padded K)
__global__ void k_xb(const float* __restrict__ x, USH* __restrict__ xb){
  const int n = 100 * 256 * 64;
  for (int i = blockIdx.x * blockDim.x + threadIdx.x; i < n; i += gridDim.x * blockDim.x){
    const int j = i & 63;
    const int b = (i >> 6) & 255;
    const int t = i >> 14;
    xb[i] = (j < 34) ? rne_bf16(x[(b * 100 + t) * 34 + j]) : (USH)0;
  }
}

// ---- per-phase kernel: phase p computes h2[p-1] (wg 64..191) and h1[p] (wg 0..63)
__global__ __launch_bounds__(256) void k_phase(
    int p, USH* __restrict__ h1b, USH* __restrict__ h2b,
    float* __restrict__ c1, float* __restrict__ c2,
    int* __restrict__ flags, float* __restrict__ part,
    const USH* __restrict__ Wcb, const float* __restrict__ bc, const float* __restrict__ b2,
    const USH* __restrict__ Whh1b, const USH* __restrict__ W2a, const USH* __restrict__ W2b,
    const USH* __restrict__ xb, float* __restrict__ out)
{
  __shared__ __attribute__((aligned(16))) char sA[2][32768];
  const int tid = threadIdx.x;
  const int w = tid >> 6, l = tid & 63;
  const int wg = blockIdx.x;
  int role, s;
  if (wg < 64)       { role = 0; s = wg;       if (p == 100) return; }
  else if (wg < 128) { role = 1; s = wg - 64;  if (p == 0)   return; }
  else               { role = 2; s = wg - 128; if (p == 0)   return; }

  const USH* h1cur = h1b + (size_t)(p & 1) * 262144;   // h1[p-1]
  const USH* h2prv = h2b + (size_t)(p & 1) * 262144;   // h2[p-2]
  const USH* Asrc = (role == 2) ? h2prv : h1cur;
  const USH* Bsrc = (role == 0) ? Whh1b : (role == 1) ? W2a : W2b;
  const int nch = (role == 0 && p == 0) ? 0 : 16;          // K=1024 as 16 chunks of 64
  const int total = nch + (role == 0 ? 1 : 0);             // +1 xg chunk for layer 1

  f32x4 acc[4][4];
#pragma unroll
  for (int i = 0; i < 4; ++i)
#pragma unroll
    for (int j = 0; j < 4; ++j) acc[i][j] = (f32x4){0.f, 0.f, 0.f, 0.f};

  const USH* xbt = xb + (size_t)p * 16384;

  // stage 256 rows x 64 bf16 cols into LDS; linear LDS dest, XOR-swizzled global source
  auto stage_chunk = [&](int kc, int buf){
    const USH* src; int rs;
    if (kc < nch) { src = Asrc + kc * 64; rs = 1024; }
    else          { src = xbt;            rs = 64;  }
#pragma unroll
    for (int i = 0; i < 8; ++i){
      const int row = (w * 8 + i) * 8 + (l >> 3);
      const int c = l & 7;
      gload16(src + (size_t)row * rs + ((c ^ (row & 7)) << 3),
              &sA[buf][(w * 8 + i) * 1024]);
    }
  };

  stage_chunk(0, 0);
  __syncthreads();

  for (int kc = 0; kc < total; ++kc){
    if (kc + 1 < total) stage_chunk(kc + 1, (kc + 1) & 1);
    const USH* Bp; int krow, kb;
    if (kc < nch) { Bp = Bsrc; krow = 1024; kb = kc * 64; }
    else          { Bp = Wcb;  krow = 64;   kb = 0; }
    const char* base = sA[kc & 1];
#pragma unroll
    for (int ks = 0; ks < 2; ++ks){
      short8 bfr[4];
      const int kk = kb + ks * 32 + ((l >> 4) << 3);
#pragma unroll
      for (int gq = 0; gq < 4; ++gq){
        const int n = gq * 1024 + s * 16 + (l & 15);
        bfr[gq] = *(const short8*)(Bp + (size_t)n * krow + kk);
      }
#pragma unroll
      for (int mf = 0; mf < 4; ++mf){
        const int row = w * 64 + mf * 16 + (l & 15);
        const int cc = ks * 4 + (l >> 4);
        short8 af = *(const short8*)(base + row * 128 + ((cc ^ (row & 7)) << 4));
#pragma unroll
        for (int gq = 0; gq < 4; ++gq)
          acc[mf][gq] = __builtin_amdgcn_mfma_f32_16x16x32_bf16(af, bfr[gq], acc[mf][gq], 0, 0, 0);
      }
    }
    __syncthreads();
  }

  const int col = s * 16 + (l & 15);
  if (role == 0){
    const float bci = bc[col], bcf = bc[1024 + col], bcg = bc[2048 + col], bco = bc[3072 + col];
    USH* h1n = h1b + (size_t)((p + 1) & 1) * 262144;
#pragma unroll
    for (int mf = 0; mf < 4; ++mf)
#pragma unroll
      for (int r = 0; r < 4; ++r){
        const int row = w * 64 + mf * 16 + ((l >> 4) << 2) + r;
        const float gi = acc[mf][0][r] + bci;
        const float gf = acc[mf][1][r] + bcf;
        const float gg = acc[mf][2][r] + bcg;
        const float go = acc[mf][3][r] + bco;
        const float cn = sigm(gf) * c1[row * 1024 + col] + sigm(gi) * tanh_(gg);
        c1[row * 1024 + col] = cn;
        h1n[row * 1024 + col] = rne_bf16(sigm(go) * tanh_(cn));
      }
  } else if (role == 1){
    float* pp = part + (size_t)s * 16384;
#pragma unroll
    for (int mf = 0; mf < 4; ++mf)
#pragma unroll
      for (int r = 0; r < 4; ++r){
        const int row = w * 64 + mf * 16 + ((l >> 4) << 2) + r;
#pragma unroll
        for (int gq = 0; gq < 4; ++gq)
          pp[row * 64 + gq * 16 + (l & 15)] = acc[mf][gq][r];
      }
    __threadfence();
    __syncthreads();
    if (tid == 0) __hip_atomic_fetch_add(&flags[s], 1, __ATOMIC_RELEASE, __HIP_MEMORY_SCOPE_AGENT);
  } else {
    if (tid == 0){
      while (__hip_atomic_load(&flags[s], __ATOMIC_ACQUIRE, __HIP_MEMORY_SCOPE_AGENT) < p) {}
    }
    __syncthreads();
    const float* pp = part + (size_t)s * 16384;
    const float b2i = b2[col], b2f = b2[1024 + col], b2g = b2[2048 + col], b2o = b2[3072 + col];
    USH* h2n = h2b + (size_t)((p + 1) & 1) * 262144;
#pragma unroll
    for (int mf = 0; mf < 4; ++mf)
#pragma unroll
      for (int r = 0; r < 4; ++r){
        const int row = w * 64 + mf * 16 + ((l >> 4) << 2) + r;
        const float gi = acc[mf][0][r] + pp[row * 64 +  0 + (l & 15)] + b2i;
        const float gf = acc[mf][1][r] + pp[row * 64 + 16 + (l & 15)] + b2f;
        const float gg = acc[mf][2][r] + pp[row * 64 + 32 + (l & 15)] + b2g;
        const float go = acc[mf][3][r] + pp[row * 64 + 48 + (l & 15)] + b2o;
        const float cn = sigm(gf) * c2[row * 1024 + col] + sigm(gi) * tanh_(gg);
        c2[row * 1024 + col] = cn;
        const float h = sigm(go) * tanh_(cn);
        if (p == 100){
          out[row * 1024 + col] = h;
          out[262144 + row * 1024 + col] = cn;
        } else {
          h2n[row * 1024 + col] = rne_bf16(h);
        }
      }
  }
}

extern "C" void kernel_launch(void* const* d_in, const int* in_sizes, int n_in,
                              void* d_out, int out_size, void* d_ws, size_t ws_size,
                              hipStream_t stream){
  const float* x    = (const float*)d_in[0];
  const float* Wlin = (const float*)d_in[1];
  const float* blin = (const float*)d_in[2];
  const float* Wih1 = (const float*)d_in[3];
  const float* Whh1 = (const float*)d_in[4];
  const float* bih1 = (const float*)d_in[5];
  const float* bhh1 = (const float*)d_in[6];
  const float* Wih2 = (const float*)d_in[7];
  const float* Whh2 = (const float*)d_in[8];
  const float* bih2 = (const float*)d_in[9];
  const float* bhh2 = (const float*)d_in[10];
  char* ws = (char*)d_ws;

  USH*   h1b   = (USH*)  (ws + 0);          // [2][256][1024] bf16
  USH*   h2b   = (USH*)  (ws + 1048576);    // [2][256][1024] bf16
  float* c1    = (float*)(ws + 2097152);    // [256][1024] f32
  float* c2    = (float*)(ws + 3145728);    // [256][1024] f32
  int*   flags = (int*)  (ws + 4194304);    // [64]
  float* part  = (float*)(ws + 4198400);    // [64][256][64] f32
  USH*   Wcb   = (USH*)  (ws + 8392704);    // [4096][64] bf16
  float* bc    = (float*)(ws + 8916992);    // [4096]
  float* b2    = (float*)(ws + 8933376);    // [4096]
  USH*   Whh1b = (USH*)  (ws + 8949760);    // [4096][1024] bf16
  USH*   W2a   = (USH*)  (ws + 17338368);   // W_ih2 bf16
  USH*   W2b   = (USH*)  (ws + 25726976);   // W_hh2 bf16
  USH*   xb    = (USH*)  (ws + 34115584);   // [100][256][64] bf16

  hipMemsetAsync(ws, 0, 4198400, stream);   // h1b, h2b, c1, c2, flags
  k_fold<<<4096, 64, 0, stream>>>(Wih1, Wlin, blin, bih1, bhh1, Wcb, bc);
  k_convert<<<4096, 256, 0, stream>>>(Whh1, Wih2, Whh2, bih2, bhh2, Whh1b, W2a, W2b, b2);
  k_xb<<<1600, 256, 0, stream>>>(x, xb);
  for (int p = 0; p <= 100; ++p)
    k_phase<<<192, 256, 0, stream>>>(p, h1b, h2b, c1, c2, flags, part,
                                     Wcb, bc, b2, Whh1b, W2a, W2b, xb, (float*)d_out);
}